// Round 7
// baseline (380.612 us; speedup 1.0000x reference)
//
#include <hip/hip_runtime.h>

#define B_  8
#define C_  128
#define H_  128
#define W_  256
#define HW_ (H_ * W_)
#define TH  8
#define TW  64
// LDS layout: 16B "units"; physical unit = u + u/8 (gap every 8 units) so an
// 8-lane group's 4 ds_read_b128 hit all 32 banks exactly once.
#define PU(u) ((u) + ((u) >> 3))
#define S2S 84                    // f2 row stride (dwords): 21 units
#define S1S 72                    // f1 row stride (dwords): 18 units
#define S1OFF (16 * S2S)          // 1344 (f2 tile = 16 rows)
#define PAIRN (S1OFF + TH * S1S)  // 1920 dwords per channel-pair tile
#define NTHREADS 576

typedef __fp16 h2 __attribute__((ext_vector_type(2)));

__device__ __forceinline__ float dot2f16(unsigned int a, unsigned int b, float c) {
#if __has_builtin(__builtin_amdgcn_fdot2)
    return __builtin_amdgcn_fdot2(__builtin_bit_cast(h2, a),
                                  __builtin_bit_cast(h2, b), c, false);
#else
    h2 ha = __builtin_bit_cast(h2, a), hb = __builtin_bit_cast(h2, b);
    return c + (float)ha.x * (float)hb.x + (float)ha.y * (float)hb.y;
#endif
}

__device__ __forceinline__ unsigned int pk(float x, float y) {
    h2 r = __builtin_amdgcn_cvt_pkrtz(x, y);
    return __builtin_bit_cast(unsigned int, r);
}

// 9-wave block, wave = di. Tile 8x64, lane owns an 8-px strip -> acc[9][8].
// Depth-2 pipeline, raw s_barrier + lgkmcnt(0) only (counted vmcnt on loads).
// Stage = 4 channels (2 f16x2 pair-tiles). Staging: slot A (all 576) = f2,
// slot B (tid<256) = f1. bounds(576,3): round-3-proven allocation regime.
__global__ __launch_bounds__(NTHREADS, 3) void cv_kernel(
    const float* __restrict__ f1g, const float* __restrict__ f2g,
    float* __restrict__ outg) {
    __shared__ __align__(16) unsigned int lds[2][2][PAIRN];

    const int tid = threadIdx.x;
    const int w0 = blockIdx.x * TW;
    const int h0 = blockIdx.y * TH;
    const int b  = blockIdx.z;

    // ---- slot A: f2 tile 16 rows x 18 units x 2 pairs = 576 slots ----
    int offA, ldA;
    float m0;
    {
        int ppA = tid / 288;
        int u   = tid % 288;
        int r   = u / 18, cu = u % 18;
        int gh = h0 - 4 + r, gw = w0 - 4 + 4 * cu;
        bool valid = (gh >= 0) && (gh < H_) && (gw >= 0) && (gw <= W_ - 4);
        int ghc = min(max(gh, 0), H_ - 1);
        int gwc = min(max(gw, 0), W_ - 4);
        offA = ((b * C_ + 2 * ppA) * H_ + ghc) * W_ + gwc;
        ldA  = r * S2S + 4 * PU(cu);
        m0   = valid ? 1.f : 0.f;
    }
    int ppA = tid / 288;
    // ---- slot B: f1 tile 8 rows x 16 units x 2 pairs = 256 slots ----
    const bool dual = (tid < 256);
    int offB = 0, ldB = 0, ppB = 0;
    if (dual) {
        ppB = tid / 128;
        int u = tid % 128;
        int r = u / 16, cu = u % 16;
        offB = ((b * C_ + 2 * ppB) * H_ + h0 + r) * W_ + w0 + 4 * cu;
        ldB  = S1OFF + r * S1S + 4 * PU(cu);
    }

#define LOADST(Sa, Sb, Sc, Sd)                                                \
    do {                                                                      \
        Sa = *(const float4*)(f2g + offA);                                    \
        Sb = *(const float4*)(f2g + offA + HW_);                              \
        offA += 4 * HW_;                                                      \
        if (dual) {                                                           \
            Sc = *(const float4*)(f1g + offB);                                \
            Sd = *(const float4*)(f1g + offB + HW_);                          \
            offB += 4 * HW_;                                                  \
        }                                                                     \
    } while (0)

#define STOREST(bi, Sa, Sb, Sc, Sd)                                           \
    do {                                                                      \
        uint4 wv;                                                             \
        wv.x = pk(Sa.x * m0, Sb.x * m0);                                      \
        wv.y = pk(Sa.y * m0, Sb.y * m0);                                      \
        wv.z = pk(Sa.z * m0, Sb.z * m0);                                      \
        wv.w = pk(Sa.w * m0, Sb.w * m0);                                      \
        *(uint4*)(&lds[bi][ppA][ldA]) = wv;                                   \
        if (dual) {                                                           \
            uint4 w2;                                                         \
            w2.x = pk(Sc.x, Sd.x);                                            \
            w2.y = pk(Sc.y, Sd.y);                                            \
            w2.z = pk(Sc.z, Sd.z);                                            \
            w2.w = pk(Sc.w, Sd.w);                                            \
            *(uint4*)(&lds[bi][ppB][ldB]) = w2;                               \
        }                                                                     \
    } while (0)

#define BAR()                                                                 \
    do {                                                                      \
        asm volatile("s_waitcnt lgkmcnt(0)" ::: "memory");                    \
        __builtin_amdgcn_s_barrier();                                         \
    } while (0)

    // ---- compute mapping: wave = di; lane -> (row hh 0..7, 8-px strip sc) ----
    const int di   = tid >> 6;
    const int lane = tid & 63;
    const int hh   = lane >> 3;
    const int sc   = lane & 7;
    int rdF2m[4], rdF1m[2];
#pragma unroll
    for (int m = 0; m < 4; ++m) {
        int u = 2 * sc + m;
        rdF2m[m] = (hh + di) * S2S + 4 * PU(u);
    }
#pragma unroll
    for (int m = 0; m < 2; ++m) {
        int u = 2 * sc + m;
        rdF1m[m] = S1OFF + hh * S1S + 4 * PU(u);
    }

    float acc[9][8];
#pragma unroll
    for (int j = 0; j < 9; ++j)
#pragma unroll
        for (int p = 0; p < 8; ++p) acc[j][p] = 0.f;

#define COMPUTE(bi)                                                           \
    do {                                                                      \
        _Pragma("unroll")                                                     \
        for (int q = 0; q < 2; ++q) {                                         \
            const unsigned int* buf = lds[bi][q];                             \
            uint4 fa = *(const uint4*)(buf + rdF2m[0]);                       \
            uint4 fb = *(const uint4*)(buf + rdF2m[1]);                       \
            uint4 fc = *(const uint4*)(buf + rdF2m[2]);                       \
            uint4 fd = *(const uint4*)(buf + rdF2m[3]);                       \
            uint4 ga = *(const uint4*)(buf + rdF1m[0]);                       \
            uint4 gb = *(const uint4*)(buf + rdF1m[1]);                       \
            unsigned int f2u[16] = {fa.x, fa.y, fa.z, fa.w, fb.x, fb.y,       \
                                    fb.z, fb.w, fc.x, fc.y, fc.z, fc.w,       \
                                    fd.x, fd.y, fd.z, fd.w};                  \
            unsigned int f1u[8]  = {ga.x, ga.y, ga.z, ga.w,                   \
                                    gb.x, gb.y, gb.z, gb.w};                  \
            _Pragma("unroll")                                                 \
            for (int j = 0; j < 9; ++j)                                       \
                _Pragma("unroll")                                             \
                for (int p = 0; p < 8; ++p)                                   \
                    acc[j][p] = dot2f16(f1u[p], f2u[p + j], acc[j][p]);       \
        }                                                                     \
    } while (0)

    float4 aA, bA, cA, dA, aB, bB, cB, dB;

    // prologue: stages 0,1 in flight; stage 0 -> LDS buf0
    LOADST(aA, bA, cA, dA);            // stage 0
    LOADST(aB, bB, cB, dB);            // stage 1
    STOREST(0, aA, bA, cA, dA);        // waits stage-0 loads only (counted)
    BAR();

    for (int s = 0; s < 30; s += 2) {
        LOADST(aA, bA, cA, dA);        // stage s+2 (in flight through compute)
        COMPUTE(0);                    // stage s
        STOREST(1, aB, bB, cB, dB);    // stage s+1
        BAR();
        LOADST(aB, bB, cB, dB);        // stage s+3
        COMPUTE(1);                    // stage s+1
        STOREST(0, aA, bA, cA, dA);    // stage s+2
        BAR();
    }
    COMPUTE(0);                        // stage 30
    STOREST(1, aB, bB, cB, dB);        // stage 31
    BAR();
    COMPUTE(1);                        // stage 31

    // ---- epilogue: mean over C and store ----
    const float inv = 1.0f / 128.0f;
    int obase = ((b * 81 + di * 9) * H_ + h0 + hh) * W_ + w0 + 8 * sc;
#pragma unroll
    for (int j = 0; j < 9; ++j) {
        float4 o0 = make_float4(acc[j][0] * inv, acc[j][1] * inv,
                                acc[j][2] * inv, acc[j][3] * inv);
        float4 o1 = make_float4(acc[j][4] * inv, acc[j][5] * inv,
                                acc[j][6] * inv, acc[j][7] * inv);
        *(float4*)(outg + obase)     = o0;
        *(float4*)(outg + obase + 4) = o1;
        obase += HW_;
    }
}

extern "C" void kernel_launch(void* const* d_in, const int* in_sizes, int n_in,
                              void* d_out, int out_size, void* d_ws, size_t ws_size,
                              hipStream_t stream) {
    const float* f1 = (const float*)d_in[0];
    const float* f2 = (const float*)d_in[1];
    float* out = (float*)d_out;
    dim3 grid(W_ / TW, H_ / TH, B_);   // 4 x 16 x 8 = 512 blocks
    cv_kernel<<<grid, NTHREADS, 0, stream>>>(f1, f2, out);
}